// Round 4
// baseline (183.604 us; speedup 1.0000x reference)
//
#include <hip/hip_runtime.h>
#include <math.h>

#define N_PTS     131072
#define G_NUMS    30
#define G_SIZE    100
#define PT_STRIDE (N_PTS / G_NUMS)   // 4369
#define BINS      4096
#define SHIFT     20
#define SAMPLE_GRPS 1024             // first 4096 points as iid sample
#define RANK_CUT  24                 // 24th-smallest sample -> tau (P(miss) ~ 1e-11)
#define CAP       2048               // global survivor cap per (b,g); E~768, +8 sigma
#define CAPB      64                 // per-block per-g LDS buffer; E~12, +15 sigma
#define TIE_CAP   64
#define CHUNK_PTS 2048               // points per filter block (512 thr x 4 pts)

__device__ __forceinline__ float dist2f(float px, float py, float pz,
                                        float qx, float qy, float qz) {
    float dx = px - qx, dy = py - qy, dz = pz - qz;
    return fmaf(dx, dx, fmaf(dy, dy, dz * dz));
}

// Smallest bin T with cumulative count >= rank. s_hist populated+synced on entry.
__device__ __forceinline__ unsigned find_bin(unsigned* s_hist, unsigned* s_wsum,
                                             unsigned* s_T, unsigned rank,
                                             int tid, int lane, int wid) {
    unsigned hv[8], csum = 0;
#pragma unroll
    for (int j = 0; j < 8; j++) { hv[j] = s_hist[tid * 8 + j]; csum += hv[j]; }
    unsigned inc = csum;
#pragma unroll
    for (int off = 1; off < 64; off <<= 1) {
        unsigned n = __shfl_up(inc, off);
        if (lane >= off) inc += n;
    }
    __syncthreads();
    if (lane == 63) s_wsum[wid] = inc;
    __syncthreads();
    unsigned base = 0;
    for (int w = 0; w < wid; w++) base += s_wsum[w];
    unsigned c = base + inc - csum;
#pragma unroll
    for (int j = 0; j < 8; j++) {
        if (c < rank && c + hv[j] >= rank) *s_T = (unsigned)(tid * 8 + j);
        c += hv[j];
    }
    __syncthreads();
    return *s_T;
}

// Coarse tau for phase 0 (strided-center queries); also zeroes counters.
__global__ __launch_bounds__(512)
void tau0_kernel(const float* __restrict__ pts, float4* __restrict__ qtau0,
                 int* __restrict__ counts, int B) {
    __shared__ unsigned s_hist[BINS];
    __shared__ unsigned s_wsum[8];
    __shared__ unsigned s_T;
    const int blk = blockIdx.x;
    const int b = blk % B, g = blk / B;
    const int gi = b * G_NUMS + g;
    const float* __restrict__ P = pts + (size_t)b * (N_PTS * 3);
    const float4* __restrict__ P4 = (const float4*)P;
    const int tid = threadIdx.x, lane = tid & 63, wid = tid >> 6;
    const float qx = P[(size_t)g * PT_STRIDE * 3 + 0];
    const float qy = P[(size_t)g * PT_STRIDE * 3 + 1];
    const float qz = P[(size_t)g * PT_STRIDE * 3 + 2];

    for (int j = tid; j < BINS; j += 512) s_hist[j] = 0u;
    if (tid == 0) s_T = 0u;
    __syncthreads();
    for (int grp = tid; grp < SAMPLE_GRPS; grp += 512) {
        float4 f0 = P4[3 * grp + 0];
        float4 f1 = P4[3 * grp + 1];
        float4 f2 = P4[3 * grp + 2];
        atomicAdd(&s_hist[__float_as_uint(dist2f(f0.x, f0.y, f0.z, qx, qy, qz)) >> SHIFT], 1u);
        atomicAdd(&s_hist[__float_as_uint(dist2f(f0.w, f1.x, f1.y, qx, qy, qz)) >> SHIFT], 1u);
        atomicAdd(&s_hist[__float_as_uint(dist2f(f1.z, f1.w, f2.x, qx, qy, qz)) >> SHIFT], 1u);
        atomicAdd(&s_hist[__float_as_uint(dist2f(f2.y, f2.z, f2.w, qx, qy, qz)) >> SHIFT], 1u);
    }
    __syncthreads();
    unsigned Tc = find_bin(s_hist, s_wsum, &s_T, RANK_CUT, tid, lane, wid);
    unsigned tau = (Tc >= BINS - 1) ? 0xFFFFFFFFu : ((Tc + 1) << SHIFT);
    if (tid == 0) {
        qtau0[gi] = make_float4(qx, qy, qz, __uint_as_float(tau));
        counts[gi] = 0;
    }
}

// Filter scan: each thread holds 4 points in registers, loops over 30 queries.
// Survivors -> per-g LDS buffers -> one global flush per (block, g).
__global__ __launch_bounds__(512)
void filter_kernel(const float* __restrict__ pts, const float4* __restrict__ qtau,
                   int* __restrict__ counts, uint2* __restrict__ surv, int B) {
    __shared__ float4 s_qt[G_NUMS];
    __shared__ int s_cnt[G_NUMS];
    __shared__ uint2 s_buf[G_NUMS][CAPB];

    const int blk = blockIdx.x;
    const int b = blk % B;                 // batch-per-XCD swizzle
    const int chunk = blk / B;             // 0..63
    const float4* __restrict__ P4 = (const float4*)(pts + (size_t)b * (N_PTS * 3));
    const int tid = threadIdx.x;
    const int lane = tid & 63, wid = tid >> 6;

    if (tid < G_NUMS) { s_qt[tid] = qtau[b * G_NUMS + tid]; s_cnt[tid] = 0; }
    __syncthreads();

    const int i0 = chunk * CHUNK_PTS + tid * 4;
    float4 f0 = P4[chunk * (CHUNK_PTS * 3 / 4) + tid * 3 + 0];
    float4 f1 = P4[chunk * (CHUNK_PTS * 3 / 4) + tid * 3 + 1];
    float4 f2 = P4[chunk * (CHUNK_PTS * 3 / 4) + tid * 3 + 2];
    const float x0 = f0.x, y0 = f0.y, z0 = f0.z;
    const float x1 = f0.w, y1 = f1.x, z1 = f1.y;
    const float x2 = f1.z, y2 = f1.w, z2 = f2.x;
    const float x3 = f2.y, y3 = f2.z, z3 = f2.w;

    for (int g = 0; g < G_NUMS; ++g) {
        float4 qt = s_qt[g];               // LDS broadcast (uniform address)
        const unsigned tau = __float_as_uint(qt.w);
        unsigned u0 = __float_as_uint(dist2f(x0, y0, z0, qt.x, qt.y, qt.z));
        unsigned u1 = __float_as_uint(dist2f(x1, y1, z1, qt.x, qt.y, qt.z));
        unsigned u2 = __float_as_uint(dist2f(x2, y2, z2, qt.x, qt.y, qt.z));
        unsigned u3 = __float_as_uint(dist2f(x3, y3, z3, qt.x, qt.y, qt.z));
#pragma unroll
        for (int j = 0; j < 4; ++j) {
            unsigned u = j == 0 ? u0 : j == 1 ? u1 : j == 2 ? u2 : u3;
            if (u < tau) {
                int p = atomicAdd(&s_cnt[g], 1);
                if (p < CAPB) {
                    s_buf[g][p] = make_uint2(u, (unsigned)(i0 + j));
                } else {                    // overflow fallback (rare)
                    int gp = atomicAdd(&counts[b * G_NUMS + g], 1);
                    if (gp < CAP)
                        surv[(size_t)(b * G_NUMS + g) * CAP + gp] =
                            make_uint2(u, (unsigned)(i0 + j));
                }
            }
        }
    }
    __syncthreads();

    // flush: one wave per g (round-robin), single global atomic per (block,g)
    for (int g = wid; g < G_NUMS; g += 8) {
        int n = s_cnt[g]; if (n > CAPB) n = CAPB;
        int base = 0;
        if (lane == 0 && n > 0) base = atomicAdd(&counts[b * G_NUMS + g], n);
        base = __shfl(base, 0);
        for (int i = lane; i < n; i += 64) {
            int p = base + i;
            if (p < CAP) surv[(size_t)(b * G_NUMS + g) * CAP + p] = s_buf[g][i];
        }
    }
}

// Exact top-100 among survivors; phase 0 -> mean + tau1, phase 1 -> covariance.
template <int PHASE>
__global__ __launch_bounds__(512)
void select_kernel(const float* __restrict__ pts,
                   const float4* __restrict__ qtau_cur,
                   float4* __restrict__ qtau_next,
                   const uint2* __restrict__ surv, int* __restrict__ counts,
                   float* __restrict__ gmeans, float* __restrict__ covs, int B) {
    __shared__ unsigned s_hist[BINS];
    __shared__ unsigned s_wsum[8];
    __shared__ unsigned s_T;
    __shared__ int s_nd, s_nt;
    __shared__ int s_sel[G_SIZE];
    __shared__ unsigned s_tu[TIE_CAP];
    __shared__ int s_ti[TIE_CAP];
    __shared__ float s_acc[3], s_cov[6];

    const int blk = blockIdx.x;
    const int b = blk % B, g = blk / B;
    const int gi = b * G_NUMS + g;
    const float* __restrict__ P = pts + (size_t)b * (N_PTS * 3);
    const float4* __restrict__ P4 = (const float4*)P;
    const int tid = threadIdx.x, lane = tid & 63, wid = tid >> 6;

    const float4 qt = qtau_cur[gi];
    const unsigned tau = __float_as_uint(qt.w);
    int S = counts[gi]; if (S > CAP) S = CAP;
    const uint2* __restrict__ sv = surv + (size_t)gi * CAP;

    for (int j = tid; j < BINS; j += 512) s_hist[j] = 0u;
    if (tid == 0) { s_T = 0u; s_nd = 0; s_nt = 0; }
    if (tid < 3) s_acc[tid] = 0.f;
    if (tid < 6) s_cov[tid] = 0.f;
    __syncthreads();

    // fine histogram over survivors
    unsigned hb = 32u - (unsigned)__clz(tau - 1u);
    unsigned sh = hb > 12u ? hb - 12u : 0u;
    for (int i = tid; i < S; i += 512) atomicAdd(&s_hist[sv[i].x >> sh], 1u);
    __syncthreads();
    unsigned T2 = find_bin(s_hist, s_wsum, &s_T, G_SIZE, tid, lane, wid);
    const unsigned lo = T2 << sh;

    for (int i = tid; i < S; i += 512) {
        unsigned u = sv[i].x;
        if (u < lo) {
            int p = atomicAdd(&s_nd, 1);
            if (p < G_SIZE) s_sel[p] = (int)sv[i].y;
        } else if ((u >> sh) == T2) {
            int p = atomicAdd(&s_nt, 1);
            if (p < TIE_CAP) { s_tu[p] = u; s_ti[p] = (int)sv[i].y; }
        }
    }
    __syncthreads();
    if (tid == 0) {
        int nd = s_nd; if (nd > G_SIZE) nd = G_SIZE;
        int need = G_SIZE - nd;
        int ec = s_nt; if (ec > TIE_CAP) ec = TIE_CAP;
        for (int a = 0; a < need && a < ec; ++a) {
            int best = a;
            for (int j = a + 1; j < ec; ++j)
                if (s_tu[j] < s_tu[best] ||
                    (s_tu[j] == s_tu[best] && s_ti[j] < s_ti[best])) best = j;
            unsigned tu = s_tu[best]; s_tu[best] = s_tu[a]; s_tu[a] = tu;
            int ti = s_ti[best]; s_ti[best] = s_ti[a]; s_ti[a] = ti;
            s_sel[nd + a] = s_ti[a];
        }
    }
    __syncthreads();

    float px = 0.f, py = 0.f, pz = 0.f;
    if (tid < G_SIZE) {
        const float* pp = P + 3 * (size_t)s_sel[tid];
        px = pp[0]; py = pp[1]; pz = pp[2];
        atomicAdd(&s_acc[0], px);
        atomicAdd(&s_acc[1], py);
        atomicAdd(&s_acc[2], pz);
    }
    __syncthreads();
    const float mx = s_acc[0] * (1.0f / G_SIZE);
    const float my = s_acc[1] * (1.0f / G_SIZE);
    const float mz = s_acc[2] * (1.0f / G_SIZE);

    if (PHASE == 0) {
        if (tid < 3) gmeans[gi * 3 + tid] = (tid == 0 ? mx : tid == 1 ? my : mz);
        // tau for phase 1 via sample scan against the mean query
        for (int j = tid; j < BINS; j += 512) s_hist[j] = 0u;
        if (tid == 0) s_T = 0u;
        __syncthreads();
        for (int grp = tid; grp < SAMPLE_GRPS; grp += 512) {
            float4 f0 = P4[3 * grp + 0];
            float4 f1 = P4[3 * grp + 1];
            float4 f2 = P4[3 * grp + 2];
            atomicAdd(&s_hist[__float_as_uint(dist2f(f0.x, f0.y, f0.z, mx, my, mz)) >> SHIFT], 1u);
            atomicAdd(&s_hist[__float_as_uint(dist2f(f0.w, f1.x, f1.y, mx, my, mz)) >> SHIFT], 1u);
            atomicAdd(&s_hist[__float_as_uint(dist2f(f1.z, f1.w, f2.x, mx, my, mz)) >> SHIFT], 1u);
            atomicAdd(&s_hist[__float_as_uint(dist2f(f2.y, f2.z, f2.w, mx, my, mz)) >> SHIFT], 1u);
        }
        __syncthreads();
        unsigned Tc = find_bin(s_hist, s_wsum, &s_T, RANK_CUT, tid, lane, wid);
        unsigned tau1 = (Tc >= BINS - 1) ? 0xFFFFFFFFu : ((Tc + 1) << SHIFT);
        if (tid == 0) {
            qtau_next[gi] = make_float4(mx, my, mz, __uint_as_float(tau1));
            counts[gi] = 0;            // reset for phase-1 filter
        }
    } else {
        if (tid < G_SIZE) {
            float x = px - mx, y = py - my, z = pz - mz;
            atomicAdd(&s_cov[0], x * x);
            atomicAdd(&s_cov[1], x * y);
            atomicAdd(&s_cov[2], x * z);
            atomicAdd(&s_cov[3], y * y);
            atomicAdd(&s_cov[4], y * z);
            atomicAdd(&s_cov[5], z * z);
        }
        __syncthreads();
        if (tid < 6) covs[gi * 6 + tid] = s_cov[tid] * (1.0f / G_SIZE);
    }
}

// ---- 3x3 symmetric eigensolve (Jacobi, double) ----
__device__ void eig3(const float cf[6], double lam_out[3], double dir_out[3]) {
    double a[3][3], v[3][3];
    a[0][0] = cf[0]; a[0][1] = cf[1]; a[0][2] = cf[2];
    a[1][0] = cf[1]; a[1][1] = cf[3]; a[1][2] = cf[4];
    a[2][0] = cf[2]; a[2][1] = cf[4]; a[2][2] = cf[5];
    for (int i = 0; i < 3; i++)
        for (int j = 0; j < 3; j++) v[i][j] = (i == j) ? 1.0 : 0.0;

    for (int sweep = 0; sweep < 12; sweep++) {
        double off = a[0][1] * a[0][1] + a[0][2] * a[0][2] + a[1][2] * a[1][2];
        if (off == 0.0) break;
        for (int p = 0; p < 2; p++) {
            for (int q = p + 1; q < 3; q++) {
                double apq = a[p][q];
                if (apq == 0.0) continue;
                double app = a[p][p], aqq = a[q][q];
                double theta = (aqq - app) / (2.0 * apq);
                double t = (theta >= 0.0 ? 1.0 : -1.0) /
                           (fabs(theta) + sqrt(theta * theta + 1.0));
                double c = 1.0 / sqrt(t * t + 1.0);
                double s = t * c;
                a[p][p] = app - t * apq;
                a[q][q] = aqq + t * apq;
                a[p][q] = 0.0; a[q][p] = 0.0;
                for (int r = 0; r < 3; r++) {
                    if (r == p || r == q) continue;
                    double arp = a[r][p], arq = a[r][q];
                    a[r][p] = c * arp - s * arq; a[p][r] = a[r][p];
                    a[r][q] = s * arp + c * arq; a[q][r] = a[r][q];
                }
                for (int r = 0; r < 3; r++) {
                    double vrp = v[r][p], vrq = v[r][q];
                    v[r][p] = c * vrp - s * vrq;
                    v[r][q] = s * vrp + c * vrq;
                }
            }
        }
    }
    double l0 = a[0][0], l1 = a[1][1], l2 = a[2][2];
    int i0 = 0, i1 = 1, i2 = 2;
    if (l0 > l1) { double t = l0; l0 = l1; l1 = t; int ti = i0; i0 = i1; i1 = ti; }
    if (l1 > l2) { double t = l1; l1 = l2; l2 = t; int ti = i1; i1 = i2; i2 = ti; }
    if (l0 > l1) { double t = l0; l0 = l1; l1 = t; int ti = i0; i0 = i1; i1 = ti; }
    lam_out[0] = l0; lam_out[1] = l1; lam_out[2] = l2;
    dir_out[0] = v[0][i2]; dir_out[1] = v[1][i2]; dir_out[2] = v[2][i2];
}

__global__ __launch_bounds__(256)
void finalize_kernel(const float* __restrict__ gmeans, const float* __restrict__ covs,
                     float* __restrict__ out, int B) {
    const int tid = threadIdx.x;
    const int NG = B * G_NUMS;   // 240
    __shared__ float s_dir[256][3];
    __shared__ float s_gm[256][3];
    __shared__ float s_pe[4];
    __shared__ float s_ps[4];

    float et = 0.f;
    if (tid < NG) {
        float cf[6];
#pragma unroll
        for (int j = 0; j < 6; j++) cf[j] = covs[tid * 6 + j];
        double lam[3], dir[3];
        eig3(cf, lam, dir);
        double denom = lam[0] + lam[1] + lam[2] + 1e-9;
        et = (float)((lam[2] - lam[1]) / denom);
        s_dir[tid][0] = (float)dir[0];
        s_dir[tid][1] = (float)dir[1];
        s_dir[tid][2] = (float)dir[2];
        s_gm[tid][0] = gmeans[tid * 3 + 0];
        s_gm[tid][1] = gmeans[tid * 3 + 1];
        s_gm[tid][2] = gmeans[tid * 3 + 2];
    }
    __syncthreads();

    float st = 0.f;
    if (tid < NG) {
        int b = tid / G_NUMS, g = tid % G_NUMS;
        float gx = s_gm[tid][0], gy = s_gm[tid][1], gz = s_gm[tid][2];
        float bd = 3.4e38f; int bj = 0;
        for (int gg = 0; gg < G_NUMS; gg++) {
            if (gg == g) continue;
            int o = b * G_NUMS + gg;
            float dx = gx - s_gm[o][0];
            float dy = gy - s_gm[o][1];
            float dz = gz - s_gm[o][2];
            float d = dx * dx + dy * dy + dz * dz;
            if (d < bd) { bd = d; bj = gg; }
        }
        int o = b * G_NUMS + bj;
        float cosv = s_dir[tid][0] * s_dir[o][0] +
                     s_dir[tid][1] * s_dir[o][1] +
                     s_dir[tid][2] * s_dir[o][2];
        st = 1.f - cosv * cosv;
    }

    float e = et, s2 = st;
#pragma unroll
    for (int off = 32; off > 0; off >>= 1) {
        e += __shfl_down(e, off);
        s2 += __shfl_down(s2, off);
    }
    int lane = tid & 63, wid = tid >> 6;
    if (lane == 0) { s_pe[wid] = e; s_ps[wid] = s2; }
    __syncthreads();
    if (tid == 0) {
        float se = 0.f, ss = 0.f;
        for (int w = 0; w < 4; w++) { se += s_pe[w]; ss += s_ps[w]; }
        out[0] = -se / (float)B + ss / (float)NG;
    }
}

extern "C" void kernel_launch(void* const* d_in, const int* in_sizes, int n_in,
                              void* d_out, int out_size, void* d_ws, size_t ws_size,
                              hipStream_t stream) {
    const float* pts = (const float*)d_in[0];
    float* out = (float*)d_out;
    int B = in_sizes[0] / (N_PTS * 3);   // 8
    const int NG = B * G_NUMS;           // 240

    // workspace layout (~4 MB)
    float4* qtau0 = (float4*)d_ws;                 // NG
    float4* qtau1 = qtau0 + NG;                    // NG
    float* gmeans = (float*)(qtau1 + NG);          // NG*3
    float* covs = gmeans + NG * 3;                 // NG*6
    int* counts = (int*)(covs + NG * 6);           // NG (pad to 256)
    uint2* surv = (uint2*)(counts + 256);          // NG*CAP*8 B

    tau0_kernel<<<NG, 512, 0, stream>>>(pts, qtau0, counts, B);
    filter_kernel<<<B * (N_PTS / CHUNK_PTS), 512, 0, stream>>>(pts, qtau0, counts, surv, B);
    select_kernel<0><<<NG, 512, 0, stream>>>(pts, qtau0, qtau1, surv, counts, gmeans, covs, B);
    filter_kernel<<<B * (N_PTS / CHUNK_PTS), 512, 0, stream>>>(pts, qtau1, counts, surv, B);
    select_kernel<1><<<NG, 512, 0, stream>>>(pts, qtau1, nullptr, surv, counts, gmeans, covs, B);
    finalize_kernel<<<1, 256, 0, stream>>>(gmeans, covs, out, B);
}